// Round 9
// baseline (917.718 us; speedup 1.0000x reference)
//
#include <hip/hip_runtime.h>
#include <hip/hip_bf16.h>

typedef unsigned short u16;
typedef __attribute__((ext_vector_type(8))) short short8x;
typedef __attribute__((ext_vector_type(4))) unsigned short ushort4x;
typedef __attribute__((ext_vector_type(4))) float f32x4;

__device__ __forceinline__ float bf2f(u16 u){
    unsigned int v = ((unsigned int)u) << 16;
    return __builtin_bit_cast(float, v);
}
__device__ __forceinline__ u16 f2bf(float f){
    __hip_bfloat16 h = __float2bfloat16(f);
    return __builtin_bit_cast(unsigned short, h);
}
__device__ __forceinline__ short8x cvt8(const float* __restrict__ p){
    const f32x4 a = *(const f32x4*)(p);
    const f32x4 b = *(const f32x4*)(p + 4);
    short8x r;
    #pragma unroll
    for (int e = 0; e < 4; ++e){ r[e] = (short)f2bf(a[e]); r[4 + e] = (short)f2bf(b[e]); }
    return r;
}
__device__ __forceinline__ void bn_pair(const float* __restrict__ bn, int base, int ch,
                                        float& sc, float& sh){
    const float g = bn[base + ch], b = bn[base + 64 + ch];
    const float m = bn[base + 128 + ch], v = bn[base + 192 + ch];
    sc = g * rsqrtf(v + 1e-5f);
    sh = b - m * sc;
}

// One block = 2 wx-adjacent 8x8 windows. 512 threads = 8 waves (0-3: win L, 4-7: win R).
// S[w][0]=A feat/qdw, S[w][1]=B q1/out, S[w][2]=C k, S[w][3]=D v.  72KB -> 2 blocks/CU.
// All global x/y traffic: 16-lane clusters cover 16 contiguous px (64B) spanning the pair.
__global__ __launch_bounds__(512, 4)
void lwa_kernel(const float* __restrict__ x,
                const float* __restrict__ q_w, const float* __restrict__ q_bn,
                const float* __restrict__ k_w, const float* __restrict__ k_bn,
                const float* __restrict__ v_w, const float* __restrict__ v_bn,
                const float* __restrict__ dw_w, const float* __restrict__ dw_bn,
                const float* __restrict__ p_w, const float* __restrict__ p_bn,
                float* __restrict__ y)
{
    __shared__ __align__(16) u16 S[2][4][64][72];

    const int tid = (int)threadIdx.x;
    const int w8  = tid >> 8;          // window within pair (compute role)
    const int t8  = tid & 255;
    const int lane = t8 & 63;
    const int wid  = t8 >> 6;          // wave within window, 0..3
    const int g    = lane >> 4;
    const int r15  = lane & 15;

    // cooperative-load role: 16-lane group G covers a 16-px row span (64B)
    const int G    = tid >> 4;         // 0..31
    const int px16 = tid & 15;
    const int lw   = px16 >> 3;        // which window this lane's element is in
    const int lpx  = px16 & 7;

    // bid swizzle: 128B-line sibling blocks (wxp 2m,2m+1) are 8 dispatches apart
    const int u = (int)blockIdx.x;
    const int m = (u & 7) | ((u >> 4) << 3);           // 0..1023
    const int half128 = (u >> 3) & 1;
    const int bimg = m >> 4, wy = (m >> 1) & 7;
    const int wxp  = ((m & 1) << 1) | half128;         // 0..3
    const size_t x_img = (size_t)bimg * (256 * 4096);
    const int pix_pair = wy * 512 + wxp * 16;          // base of the pair's 16-px span

    // S0: head-0 chunk -> A (both windows), 64B-coalesced
    #pragma unroll
    for (int j = 0; j < 16; ++j){
        const int s = G + 32 * j, c = s >> 3, py = s & 7;
        const float v = x[x_img + (size_t)c * 4096 + pix_pair + py * 64 + px16];
        S[lw][0][py * 8 + lpx][c] = f2bf(v);
    }

    // projection accumulators: wave `wid` (per window) owns output rows [64*wid, 64*wid+64)
    f32x4 pacc[4][4];
    #pragma unroll
    for (int a = 0; a < 4; ++a)
        #pragma unroll
        for (int b = 0; b < 4; ++b)
            pacc[a][b] = (f32x4){0.f, 0.f, 0.f, 0.f};

    const int o0 = wid * 16 + g * 4;   // qkv output-channel base

    for (int i = 0; i < 4; ++i){
        __syncthreads();   // A(feat) ready; B free

        // ---- stage 1: fused q/k/v MFMA + BN ----
        {
            const int arow = (wid * 16 + r15) * 64 + g * 8;
            const short8x qa0 = cvt8(q_w + i * 4096 + arow);
            const short8x qa1 = cvt8(q_w + i * 4096 + arow + 32);
            const short8x ka0 = cvt8(k_w + i * 4096 + arow);
            const short8x ka1 = cvt8(k_w + i * 4096 + arow + 32);
            const short8x va0 = cvt8(v_w + i * 4096 + arow);
            const short8x va1 = cvt8(v_w + i * 4096 + arow + 32);
            float scq4[4], shq4[4], sck4[4], shk4[4], scv4[4], shv4[4];
            #pragma unroll
            for (int r = 0; r < 4; ++r){
                bn_pair(q_bn, i * 256, o0 + r, scq4[r], shq4[r]);
                bn_pair(k_bn, i * 256, o0 + r, sck4[r], shk4[r]);
                bn_pair(v_bn, i * 256, o0 + r, scv4[r], shv4[r]);
            }
            #pragma unroll
            for (int tc = 0; tc < 4; ++tc){
                const short8x b0 = *(const short8x*)(&S[w8][0][tc * 16 + r15][g * 8]);
                const short8x b1 = *(const short8x*)(&S[w8][0][tc * 16 + r15][32 + g * 8]);
                f32x4 accq = (f32x4){0.f, 0.f, 0.f, 0.f};
                f32x4 acck = (f32x4){0.f, 0.f, 0.f, 0.f};
                f32x4 accv = (f32x4){0.f, 0.f, 0.f, 0.f};
                accq = __builtin_amdgcn_mfma_f32_16x16x32_bf16(qa0, b0, accq, 0, 0, 0);
                accq = __builtin_amdgcn_mfma_f32_16x16x32_bf16(qa1, b1, accq, 0, 0, 0);
                acck = __builtin_amdgcn_mfma_f32_16x16x32_bf16(ka0, b0, acck, 0, 0, 0);
                acck = __builtin_amdgcn_mfma_f32_16x16x32_bf16(ka1, b1, acck, 0, 0, 0);
                accv = __builtin_amdgcn_mfma_f32_16x16x32_bf16(va0, b0, accv, 0, 0, 0);
                accv = __builtin_amdgcn_mfma_f32_16x16x32_bf16(va1, b1, accv, 0, 0, 0);
                const int n2 = tc * 16 + r15;
                #pragma unroll
                for (int r = 0; r < 4; ++r){
                    S[w8][1][o0 + r][n2] = f2bf(accq[r] * scq4[r] + shq4[r]);   // q1 [ch][tok]
                    S[w8][2][o0 + r][n2] = f2bf(acck[r] * sck4[r] + shk4[r]);   // k  [ch][tok]
                }
                ushort4x pk;
                #pragma unroll
                for (int r = 0; r < 4; ++r) pk[r] = f2bf(accv[r] * scv4[r] + shv4[r]);
                *(ushort4x*)(&S[w8][3][n2][o0]) = pk;                           // v  [tok][ch]
            }
        }

        // prefetch next head's x chunk (64B-coalesced) into registers
        float pre[16];
        if (i < 3){
            #pragma unroll
            for (int j = 0; j < 16; ++j){
                const int s = G + 32 * j, c = s >> 3, py = s & 7;
                pre[j] = x[x_img + (size_t)((i + 1) * 64 + c) * 4096 + pix_pair + py * 64 + px16];
            }
        }
        __syncthreads();

        // ---- stage 2: depthwise 5x5 + BN; q1(B) -> qdw(A [tok][ch]) ----
        {
            const int c = t8 & 63, w2 = wid;
            float rin[6][8];
            #pragma unroll
            for (int rr = 0; rr < 6; ++rr){
                const int ry = 2 * w2 - 2 + rr;
                if (ry >= 0 && ry < 8){
                    short8x rv = *(const short8x*)(&S[w8][1][c][ry * 8]);
                    #pragma unroll
                    for (int e = 0; e < 8; ++e) rin[rr][e] = bf2f((u16)rv[e]);
                } else {
                    #pragma unroll
                    for (int e = 0; e < 8; ++e) rin[rr][e] = 0.f;
                }
            }
            float wt[25];
            const float* dwp = dw_w + (i * 64 + c) * 25;
            #pragma unroll
            for (int t5 = 0; t5 < 25; ++t5) wt[t5] = dwp[t5];
            float sc, sh;
            bn_pair(dw_bn, i * 256, c, sc, sh);
            #pragma unroll
            for (int oy = 0; oy < 2; ++oy){
                #pragma unroll
                for (int px = 0; px < 8; ++px){
                    float acc = 0.f;
                    #pragma unroll
                    for (int ky = 0; ky < 5; ++ky){
                        #pragma unroll
                        for (int kx = 0; kx < 5; ++kx){
                            const int ix = px - 2 + kx;
                            if (ix >= 0 && ix < 8) acc += rin[oy + ky][ix] * wt[ky * 5 + kx];
                        }
                    }
                    S[w8][0][(2 * w2 + oy) * 8 + px][c] = f2bf(acc * sc + sh);
                }
            }
        }
        __syncthreads();

        // ---- stage 3: attention; out -> B [tok][ch] ----
        {
            const int n = t8 >> 2, j = t8 & 3, c0 = j * 16;
            short8x qa0 = *(const short8x*)(&S[w8][0][n][c0]);
            short8x qa1 = *(const short8x*)(&S[w8][0][n][c0 + 8]);
            short8x ka0 = *(const short8x*)(&S[w8][2][n][c0]);
            short8x ka1 = *(const short8x*)(&S[w8][2][n][c0 + 8]);
            short8x va0 = *(const short8x*)(&S[w8][3][n][c0]);
            short8x va1 = *(const short8x*)(&S[w8][3][n][c0 + 8]);
            float s[16];
            #pragma unroll
            for (int e = 0; e < 8; ++e){
                s[e]     = bf2f((u16)qa0[e]) * bf2f((u16)ka0[e]);
                s[8 + e] = bf2f((u16)qa1[e]) * bf2f((u16)ka1[e]);
            }
            float mx = s[0];
            #pragma unroll
            for (int e = 1; e < 16; ++e) mx = fmaxf(mx, s[e]);
            mx = fmaxf(mx, __shfl_xor(mx, 1));
            mx = fmaxf(mx, __shfl_xor(mx, 2));
            float sum = 0.f;
            #pragma unroll
            for (int e = 0; e < 16; ++e){ s[e] = __expf(s[e] - mx); sum += s[e]; }
            sum += __shfl_xor(sum, 1);
            sum += __shfl_xor(sum, 2);
            const float inv = 1.f / sum;
            short8x o0v, o1v;
            #pragma unroll
            for (int e = 0; e < 8; ++e){
                o0v[e] = (short)f2bf(bf2f((u16)va0[e]) * s[e] * inv);
                o1v[e] = (short)f2bf(bf2f((u16)va1[e]) * s[8 + e] * inv);
            }
            *(short8x*)(&S[w8][1][n][c0])     = o0v;
            *(short8x*)(&S[w8][1][n][c0 + 8]) = o1v;
        }
        __syncthreads();

        // ---- stage 3b: cascade next feat = pre + out (A <- pre + B) ----
        if (i < 3){
            #pragma unroll
            for (int j = 0; j < 16; ++j){
                const int s = G + 32 * j, c = s >> 3, py = s & 7;
                const int tok = py * 8 + lpx;
                S[lw][0][tok][c] = f2bf(pre[j] + bf2f(S[lw][1][tok][c]));
            }
        }

        // ---- stage 4: incremental projection pacc += p_w[:, 64i:64i+64] @ B^T ----
        {
            #pragma unroll
            for (int rt = 0; rt < 4; ++rt){
                #pragma unroll
                for (int kk = 0; kk < 2; ++kk){
                    const short8x a = cvt8(p_w + (size_t)(wid * 64 + rt * 16 + r15) * 256
                                           + i * 64 + kk * 32 + g * 8);
                    #pragma unroll
                    for (int tc = 0; tc < 4; ++tc){
                        short8x b = *(const short8x*)(&S[w8][1][tc * 16 + r15][kk * 32 + g * 8]);
                        pacc[rt][tc] = __builtin_amdgcn_mfma_f32_16x16x32_bf16(a, b, pacc[rt][tc], 0, 0, 0);
                    }
                }
            }
        }
    }

    // ---- epilogue: BN + LDS-staged 64B-coalesced fp32 stores, 4 rounds of 64 channels ----
    float* ebufW = (float*)&S[w8][0][0][0];    // [64][65] fp32 view, per window (16.6KB < 36.8KB)
    float* ebufL = (float*)&S[lw][0][0][0];
    for (int rt = 0; rt < 4; ++rt){
        __syncthreads();   // B(out)/prev-round reads done
        float sc4[4], sh4[4];
        #pragma unroll
        for (int r = 0; r < 4; ++r){
            const int o = wid * 64 + rt * 16 + g * 4 + r;
            const float gg = p_bn[o], bb = p_bn[256 + o], mm = p_bn[512 + o], vv = p_bn[768 + o];
            sc4[r] = gg * rsqrtf(vv + 1e-5f);
            sh4[r] = bb - mm * sc4[r];
        }
        #pragma unroll
        for (int tc = 0; tc < 4; ++tc){
            #pragma unroll
            for (int r = 0; r < 4; ++r){
                const int cc = wid * 16 + g * 4 + r;          // channel-in-chunk
                ebufW[cc * 65 + tc * 16 + r15] = pacc[rt][tc][r] * sc4[r] + sh4[r];
            }
        }
        __syncthreads();
        #pragma unroll
        for (int j = 0; j < 16; ++j){
            const int s = G + 32 * j, cc = s >> 3, py = s & 7;
            const int o = ((cc >> 4) << 6) + rt * 16 + (cc & 15);
            y[x_img + (size_t)o * 4096 + pix_pair + py * 64 + px16]
                = ebufL[cc * 65 + py * 8 + lpx];
        }
    }
}

extern "C" void kernel_launch(void* const* d_in, const int* in_sizes, int n_in,
                              void* d_out, int out_size, void* d_ws, size_t ws_size,
                              hipStream_t stream) {
    const float* x    = (const float*)d_in[0];
    const float* q_w  = (const float*)d_in[1];
    const float* q_bn = (const float*)d_in[2];
    const float* k_w  = (const float*)d_in[3];
    const float* k_bn = (const float*)d_in[4];
    const float* v_w  = (const float*)d_in[5];
    const float* v_bn = (const float*)d_in[6];
    const float* dw_w = (const float*)d_in[7];
    const float* dw_bn= (const float*)d_in[8];
    const float* p_w  = (const float*)d_in[9];
    const float* p_bn = (const float*)d_in[10];
    float* yout = (float*)d_out;
    lwa_kernel<<<dim3(2048), dim3(512), 0, stream>>>(x, q_w, q_bn, k_w, k_bn, v_w, v_bn,
                                                     dw_w, dw_bn, p_w, p_bn, yout);
}

// Round 10
// 665.289 us; speedup vs baseline: 1.3794x; 1.3794x over previous
//
#include <hip/hip_runtime.h>
#include <hip/hip_bf16.h>

typedef unsigned short u16;
typedef __attribute__((ext_vector_type(8))) short short8x;
typedef __attribute__((ext_vector_type(4))) unsigned short ushort4x;
typedef __attribute__((ext_vector_type(4))) float f32x4;

__device__ __forceinline__ float bf2f(u16 u){
    unsigned int v = ((unsigned int)u) << 16;
    return __builtin_bit_cast(float, v);
}
__device__ __forceinline__ u16 f2bf(float f){
    __hip_bfloat16 h = __float2bfloat16(f);
    return __builtin_bit_cast(unsigned short, h);
}
__device__ __forceinline__ short8x cvt8(const float* __restrict__ p){
    const f32x4 a = *(const f32x4*)(p);
    const f32x4 b = *(const f32x4*)(p + 4);
    short8x r;
    #pragma unroll
    for (int e = 0; e < 4; ++e){ r[e] = (short)f2bf(a[e]); r[4 + e] = (short)f2bf(b[e]); }
    return r;
}
__device__ __forceinline__ void bn_pair(const float* __restrict__ bn, int base, int ch,
                                        float& sc, float& sh){
    const float g = bn[base + ch], b = bn[base + 64 + ch];
    const float m = bn[base + 128 + ch], v = bn[base + 192 + ch];
    sc = g * rsqrtf(v + 1e-5f);
    sh = b - m * sc;
}

// One block = one 8x8 window (round-8 proven core). 256 threads = 4 waves.
// USE_WS=1: epilogue stores windowized ywin[win][oc][tok] fp32 to d_ws, fully
// contiguous (1KB per wave-instruction) -> no partial-line write-allocate.
// USE_WS=0: fallback = round-8 direct-y epilogue.
template<int USE_WS>
__global__ __launch_bounds__(256, 4)
void lwa_kernel(const float* __restrict__ x,
                const float* __restrict__ q_w, const float* __restrict__ q_bn,
                const float* __restrict__ k_w, const float* __restrict__ k_bn,
                const float* __restrict__ v_w, const float* __restrict__ v_bn,
                const float* __restrict__ dw_w, const float* __restrict__ dw_bn,
                const float* __restrict__ p_w, const float* __restrict__ p_bn,
                float* __restrict__ yout)   // ywin if USE_WS else y
{
    __shared__ __align__(16) u16 S[4][64][72];   // A,B,C,D
    u16 (*A)[72] = S[0];
    u16 (*B)[72] = S[1];
    u16 (*C)[72] = S[2];
    u16 (*D)[72] = S[3];

    const int tid  = (int)threadIdx.x;
    const int lane = tid & 63;
    const int wid  = tid >> 6;
    const int g    = lane >> 4;
    const int r15  = lane & 15;

    // XCD swizzle, temporally tight (round-8)
    const int hbid = (int)blockIdx.x;
    const int t    = hbid >> 3;
    const int wndw = (hbid & 7) * 512 + (t >> 3) * 8 + (t & 7);
    const int bimg = wndw >> 6;
    const int wy   = (wndw >> 3) & 7;
    const int wx   = wndw & 7;
    const size_t x_img = (size_t)bimg * (256 * 4096);
    const int pix_base = wy * 8 * 64 + wx * 8;

    // head-0 chunk -> A[tok][ch]
    {
        const int c = tid >> 2, qq = tid & 3;
        const float* xp = x + x_img + (size_t)c * 4096 + pix_base;
        #pragma unroll
        for (int rr = 0; rr < 2; ++rr){
            const int py = qq * 2 + rr;
            f32x4 r0 = *(const f32x4*)(xp + py * 64);
            f32x4 r1 = *(const f32x4*)(xp + py * 64 + 4);
            #pragma unroll
            for (int px = 0; px < 4; ++px){
                A[py * 8 + px][c]     = f2bf(r0[px]);
                A[py * 8 + 4 + px][c] = f2bf(r1[px]);
            }
        }
    }

    f32x4 pacc[4][4];
    #pragma unroll
    for (int a = 0; a < 4; ++a)
        #pragma unroll
        for (int b = 0; b < 4; ++b)
            pacc[a][b] = (f32x4){0.f, 0.f, 0.f, 0.f};

    const int o0 = wid * 16 + g * 4;

    for (int i = 0; i < 4; ++i){
        __syncthreads();

        // ---- stage 1: fused q/k/v MFMA + BN ----
        {
            const int arow = (wid * 16 + r15) * 64 + g * 8;
            const short8x qa0 = cvt8(q_w + i * 4096 + arow);
            const short8x qa1 = cvt8(q_w + i * 4096 + arow + 32);
            const short8x ka0 = cvt8(k_w + i * 4096 + arow);
            const short8x ka1 = cvt8(k_w + i * 4096 + arow + 32);
            const short8x va0 = cvt8(v_w + i * 4096 + arow);
            const short8x va1 = cvt8(v_w + i * 4096 + arow + 32);
            float scq4[4], shq4[4], sck4[4], shk4[4], scv4[4], shv4[4];
            #pragma unroll
            for (int r = 0; r < 4; ++r){
                bn_pair(q_bn, i * 256, o0 + r, scq4[r], shq4[r]);
                bn_pair(k_bn, i * 256, o0 + r, sck4[r], shk4[r]);
                bn_pair(v_bn, i * 256, o0 + r, scv4[r], shv4[r]);
            }
            #pragma unroll
            for (int tc = 0; tc < 4; ++tc){
                const short8x b0 = *(const short8x*)(&A[tc * 16 + r15][g * 8]);
                const short8x b1 = *(const short8x*)(&A[tc * 16 + r15][32 + g * 8]);
                f32x4 accq = (f32x4){0.f, 0.f, 0.f, 0.f};
                f32x4 acck = (f32x4){0.f, 0.f, 0.f, 0.f};
                f32x4 accv = (f32x4){0.f, 0.f, 0.f, 0.f};
                accq = __builtin_amdgcn_mfma_f32_16x16x32_bf16(qa0, b0, accq, 0, 0, 0);
                accq = __builtin_amdgcn_mfma_f32_16x16x32_bf16(qa1, b1, accq, 0, 0, 0);
                acck = __builtin_amdgcn_mfma_f32_16x16x32_bf16(ka0, b0, acck, 0, 0, 0);
                acck = __builtin_amdgcn_mfma_f32_16x16x32_bf16(ka1, b1, acck, 0, 0, 0);
                accv = __builtin_amdgcn_mfma_f32_16x16x32_bf16(va0, b0, accv, 0, 0, 0);
                accv = __builtin_amdgcn_mfma_f32_16x16x32_bf16(va1, b1, accv, 0, 0, 0);
                const int n2 = tc * 16 + r15;
                #pragma unroll
                for (int r = 0; r < 4; ++r){
                    B[o0 + r][n2] = f2bf(accq[r] * scq4[r] + shq4[r]);
                    C[o0 + r][n2] = f2bf(acck[r] * sck4[r] + shk4[r]);
                }
                ushort4x pk;
                #pragma unroll
                for (int r = 0; r < 4; ++r) pk[r] = f2bf(accv[r] * scv4[r] + shv4[r]);
                *(ushort4x*)(&D[n2][o0]) = pk;
            }
        }
        __syncthreads();

        // ---- stage 2: depthwise 5x5 + BN; q1(B) -> qdw(A) ----
        {
            const int c = tid & 63, w2 = wid;
            float rin[6][8];
            #pragma unroll
            for (int rr = 0; rr < 6; ++rr){
                const int ry = 2 * w2 - 2 + rr;
                if (ry >= 0 && ry < 8){
                    short8x rv = *(const short8x*)(&B[c][ry * 8]);
                    #pragma unroll
                    for (int e = 0; e < 8; ++e) rin[rr][e] = bf2f((u16)rv[e]);
                } else {
                    #pragma unroll
                    for (int e = 0; e < 8; ++e) rin[rr][e] = 0.f;
                }
            }
            float wt[25];
            const float* dwp = dw_w + (i * 64 + c) * 25;
            #pragma unroll
            for (int t5 = 0; t5 < 25; ++t5) wt[t5] = dwp[t5];
            float sc, sh;
            bn_pair(dw_bn, i * 256, c, sc, sh);
            #pragma unroll
            for (int oy = 0; oy < 2; ++oy){
                #pragma unroll
                for (int px = 0; px < 8; ++px){
                    float acc = 0.f;
                    #pragma unroll
                    for (int ky = 0; ky < 5; ++ky){
                        #pragma unroll
                        for (int kx = 0; kx < 5; ++kx){
                            const int ix = px - 2 + kx;
                            if (ix >= 0 && ix < 8) acc += rin[oy + ky][ix] * wt[ky * 5 + kx];
                        }
                    }
                    A[(2 * w2 + oy) * 8 + px][c] = f2bf(acc * sc + sh);
                }
            }
        }
        __syncthreads();

        // ---- stage 3: attention; out -> B [tok][ch]; next feat -> A ----
        {
            const int n = tid >> 2, j = tid & 3, c0 = j * 16;
            short8x qa0 = *(const short8x*)(&A[n][c0]);
            short8x qa1 = *(const short8x*)(&A[n][c0 + 8]);
            short8x ka0 = *(const short8x*)(&C[n][c0]);
            short8x ka1 = *(const short8x*)(&C[n][c0 + 8]);
            short8x va0 = *(const short8x*)(&D[n][c0]);
            short8x va1 = *(const short8x*)(&D[n][c0 + 8]);
            float s[16];
            #pragma unroll
            for (int e = 0; e < 8; ++e){
                s[e]     = bf2f((u16)qa0[e]) * bf2f((u16)ka0[e]);
                s[8 + e] = bf2f((u16)qa1[e]) * bf2f((u16)ka1[e]);
            }
            float mx = s[0];
            #pragma unroll
            for (int e = 1; e < 16; ++e) mx = fmaxf(mx, s[e]);
            mx = fmaxf(mx, __shfl_xor(mx, 1));
            mx = fmaxf(mx, __shfl_xor(mx, 2));
            float sum = 0.f;
            #pragma unroll
            for (int e = 0; e < 16; ++e){ s[e] = __expf(s[e] - mx); sum += s[e]; }
            sum += __shfl_xor(sum, 1);
            sum += __shfl_xor(sum, 2);
            const float inv = 1.f / sum;
            float ov[16];
            #pragma unroll
            for (int e = 0; e < 8; ++e){
                ov[e]     = bf2f((u16)va0[e]) * s[e] * inv;
                ov[8 + e] = bf2f((u16)va1[e]) * s[8 + e] * inv;
            }
            short8x o0v, o1v;
            #pragma unroll
            for (int e = 0; e < 8; ++e){ o0v[e] = (short)f2bf(ov[e]); o1v[e] = (short)f2bf(ov[8 + e]); }
            *(short8x*)(&B[n][c0])     = o0v;
            *(short8x*)(&B[n][c0 + 8]) = o1v;
            if (i < 3){
                const int py = n >> 3, px = n & 7;
                const float* xc = x + x_img + pix_base + py * 64 + px + (size_t)((i + 1) * 64 + c0) * 4096;
                short8x f0v, f1v;
                #pragma unroll
                for (int e = 0; e < 8; ++e){
                    f0v[e] = (short)f2bf(xc[(size_t)e * 4096]       + ov[e]);
                    f1v[e] = (short)f2bf(xc[(size_t)(e + 8) * 4096] + ov[8 + e]);
                }
                *(short8x*)(&A[n][c0])     = f0v;
                *(short8x*)(&A[n][c0 + 8]) = f1v;
            }
        }
        __syncthreads();

        // ---- stage 4: projection pacc += p_w[:, 64i:64i+64] @ B^T ----
        {
            #pragma unroll
            for (int rt = 0; rt < 4; ++rt){
                #pragma unroll
                for (int kk = 0; kk < 2; ++kk){
                    const short8x a = cvt8(p_w + (size_t)(wid * 64 + rt * 16 + r15) * 256
                                           + i * 64 + kk * 32 + g * 8);
                    #pragma unroll
                    for (int tc = 0; tc < 4; ++tc){
                        short8x b = *(const short8x*)(&B[tc * 16 + r15][kk * 32 + g * 8]);
                        pacc[rt][tc] = __builtin_amdgcn_mfma_f32_16x16x32_bf16(a, b, pacc[rt][tc], 0, 0, 0);
                    }
                }
            }
        }
    }

    if (USE_WS){
        // ---- epilogue: BN -> LDS [64][68] f32 -> fully-contiguous ywin store ----
        float* ep = (float*)&S[0][0][0];                 // 64*68*4 = 17408B (A+B dead)
        for (int rt = 0; rt < 4; ++rt){
            __syncthreads();                             // prior readers of S done
            #pragma unroll
            for (int r = 0; r < 4; ++r){
                const int o = wid * 64 + rt * 16 + g * 4 + r;
                const float gg = p_bn[o], bb = p_bn[256 + o], mm = p_bn[512 + o], vv = p_bn[768 + o];
                const float sc = gg * rsqrtf(vv + 1e-5f);
                const float sh = bb - mm * sc;
                const int row = wid * 16 + g * 4 + r;
                #pragma unroll
                for (int tc = 0; tc < 4; ++tc)
                    ep[row * 68 + tc * 16 + r15] = pacc[rt][tc][r] * sc + sh;
            }
            __syncthreads();
            // coop store: 1KB contiguous per wave-instruction
            const int c4 = tid >> 6, oc_l = (tid & 63) >> 2, tok0 = (tid & 3) * 16;
            const int row = c4 * 16 + oc_l;
            const int o   = c4 * 64 + rt * 16 + oc_l;
            float* dst = yout + (size_t)wndw * 16384 + o * 64 + tok0;
            const float* src = ep + row * 68 + tok0;
            #pragma unroll
            for (int k = 0; k < 4; ++k)
                *(f32x4*)(dst + k * 4) = *(const f32x4*)(src + k * 4);
        }
    } else {
        // ---- fallback: round-8 direct-y epilogue ----
        #pragma unroll
        for (int rt = 0; rt < 4; ++rt){
            float sc4[4], sh4[4];
            #pragma unroll
            for (int r = 0; r < 4; ++r){
                const int o = wid * 64 + rt * 16 + g * 4 + r;
                const float gg = p_bn[o], bb = p_bn[256 + o], mm = p_bn[512 + o], vv = p_bn[768 + o];
                sc4[r] = gg * rsqrtf(vv + 1e-5f);
                sh4[r] = bb - mm * sc4[r];
            }
            #pragma unroll
            for (int tc = 0; tc < 4; ++tc){
                #pragma unroll
                for (int r = 0; r < 4; ++r){
                    const int o = wid * 64 + rt * 16 + g * 4 + r;
                    const int n = tc * 16 + r15;
                    const int py = n >> 3, px = n & 7;
                    yout[x_img + (size_t)o * 4096 + pix_base + py * 64 + px]
                        = pacc[rt][tc][r] * sc4[r] + sh4[r];
                }
            }
        }
    }
}

// ywin [win][oc][tok] fp32 -> y [img][oc][row][px], full-line both sides.
__global__ __launch_bounds__(256)
void yxform(const float* __restrict__ ywin, float* __restrict__ y)
{
    __shared__ __align__(16) float lds[8 * 1092];   // win stride 1092, oc stride 68
    const int b = (int)blockIdx.x;                  // 8192 = 64 img x 8 wy x 16 cg
    const int img = b >> 7, wy = (b >> 4) & 7, cg = b & 15;
    const int t = (int)threadIdx.x;

    // phase 1: read 8 win x 16 oc x 64 tok (contiguous 4KB runs per window)
    {
        const int win_l = t >> 5, r5 = t & 31, oc = r5 >> 1, tokh = (r5 & 1) * 32;
        const int win_g = img * 64 + wy * 8 + win_l;
        const float* src = ywin + (size_t)win_g * 16384 + (cg * 16 + oc) * 64 + tokh;
        float* dst = lds + win_l * 1092 + oc * 68 + tokh;
        #pragma unroll
        for (int k = 0; k < 8; ++k)
            *(f32x4*)(dst + k * 4) = *(const f32x4*)(src + k * 4);
    }
    __syncthreads();

    // phase 2: write y, 1KB contiguous per wave-instruction (full rows)
    {
        const int wv = t >> 6, L = t & 63;
        #pragma unroll
        for (int k = 0; k < 8; ++k){
            const int r = wv * 8 + k, oc = r >> 1, pyh = r & 1;
            const int py = pyh * 4 + (L >> 4), px4 = (L & 15) * 4;
            const int win_l = px4 >> 3, tok = py * 8 + (px4 & 7);
            const f32x4 v = *(const f32x4*)(lds + win_l * 1092 + oc * 68 + tok);
            *(f32x4*)(y + (size_t)(img * 256 + cg * 16 + oc) * 4096
                        + (wy * 8 + py) * 64 + px4) = v;
        }
    }
}

extern "C" void kernel_launch(void* const* d_in, const int* in_sizes, int n_in,
                              void* d_out, int out_size, void* d_ws, size_t ws_size,
                              hipStream_t stream) {
    const float* x    = (const float*)d_in[0];
    const float* q_w  = (const float*)d_in[1];
    const float* q_bn = (const float*)d_in[2];
    const float* k_w  = (const float*)d_in[3];
    const float* k_bn = (const float*)d_in[4];
    const float* v_w  = (const float*)d_in[5];
    const float* v_bn = (const float*)d_in[6];
    const float* dw_w = (const float*)d_in[7];
    const float* dw_bn= (const float*)d_in[8];
    const float* p_w  = (const float*)d_in[9];
    const float* p_bn = (const float*)d_in[10];
    float* yout = (float*)d_out;

    const size_t need = (size_t)4096 * 16384 * 4;   // 268435456 B
    if (ws_size >= need){
        float* ywin = (float*)d_ws;
        lwa_kernel<1><<<dim3(4096), dim3(256), 0, stream>>>(x, q_w, q_bn, k_w, k_bn, v_w, v_bn,
                                                            dw_w, dw_bn, p_w, p_bn, ywin);
        yxform<<<dim3(8192), dim3(256), 0, stream>>>(ywin, yout);
    } else {
        lwa_kernel<0><<<dim3(4096), dim3(256), 0, stream>>>(x, q_w, q_bn, k_w, k_bn, v_w, v_bn,
                                                            dw_w, dw_bn, p_w, p_bn, yout);
    }
}